// Round 3
// baseline (667.918 us; speedup 1.0000x reference)
//
#include <hip/hip_runtime.h>
#include <hip/hip_bf16.h>
#include <cstdint>
#include <cstddef>

// Problem constants
#define BATCH   8192
#define DIM     768
#define NTOT    6291456      // BATCH*DIM
#define NLAYERS 4

typedef _Float16 half8 __attribute__((ext_vector_type(8)));
typedef float    f32x4 __attribute__((ext_vector_type(4)));

#define AS_GLOBAL __attribute__((address_space(1)))
#define AS_LDS    __attribute__((address_space(3)))

// async 16B global->LDS copy; lds dst is wave-uniform base + lane*16
__device__ __forceinline__ void async_copy16(const void* g, void* l) {
  __builtin_amdgcn_global_load_lds((AS_GLOBAL const uint32_t*)g,
                                   (AS_LDS uint32_t*)l, 16, 0, 0);
}

// ---------------------------------------------------------------------------
// Swizzled global layouts (granule = 8 halves = 16B):
//   x*:  [t 24][kk 4][b 8192][8]          granule idx = (t*4+kk)*8192 + b
//   W*:  [net][layer][t 24][kk 4][row 768][8]
//   cr*: [g16 48][b 8192][16 floats]      g16 = f>>4  (64B granule)
// logical element (b, f): t = f>>5, kk = (f>>3)&3, e = f&7
// ---------------------------------------------------------------------------

// ---------------------------------------------------------------------------
// Threefry-2x32 (matches jax/_src/prng.py exactly; 20 rounds, 5 key injections)
// ---------------------------------------------------------------------------
__host__ __device__ __forceinline__ uint32_t rotl32(uint32_t v, int d) {
  return (v << d) | (v >> (32 - d));
}

__host__ __device__ __forceinline__ void threefry2x32(
    uint32_t k0, uint32_t k1, uint32_t x0, uint32_t x1,
    uint32_t& o0, uint32_t& o1) {
  uint32_t ks2 = k0 ^ k1 ^ 0x1BD11BDAu;
  x0 += k0; x1 += k1;
#define TF_R(r) { x0 += x1; x1 = rotl32(x1, (r)) ^ x0; }
  TF_R(13) TF_R(15) TF_R(26) TF_R(6)
  x0 += k1; x1 += ks2 + 1u;
  TF_R(17) TF_R(29) TF_R(16) TF_R(24)
  x0 += ks2; x1 += k0 + 2u;
  TF_R(13) TF_R(15) TF_R(26) TF_R(6)
  x0 += k0; x1 += k1 + 3u;
  TF_R(17) TF_R(29) TF_R(16) TF_R(24)
  x0 += k1; x1 += ks2 + 4u;
  TF_R(13) TF_R(15) TF_R(26) TF_R(6)
  x0 += ks2; x1 += k0 + 5u;
#undef TF_R
  o0 = x0; o1 = x1;
}

__device__ __forceinline__ double sigmoid_d(double x) {
  return 1.0 / (1.0 + exp(-x));
}

// fast f64 e^x, clamped, rel err ~2e-13
__device__ __forceinline__ double dexp(double x) {
  x = fmin(fmax(x, -708.0), 708.0);
  const double LOG2E = 1.4426950408889634;
  const double LN2   = 0.6931471805599453;
  double t = x * LOG2E;
  double n = rint(t);
  double g = (t - n) * LN2;
  double r = 2.7557319223985893e-07;
  r = r * g + 2.7557319223985888e-06;
  r = r * g + 2.4801587301587302e-05;
  r = r * g + 1.9841269841269841e-04;
  r = r * g + 1.3888888888888889e-03;
  r = r * g + 8.3333333333333332e-03;
  r = r * g + 4.1666666666666664e-02;
  r = r * g + 1.6666666666666666e-01;
  r = r * g + 0.5;
  r = r * g + 1.0;
  r = r * g + 1.0;
  int ni = (int)n;
  double sc = __longlong_as_double(((long long)(1023 + ni)) << 52);
  return r * sc;
}

// ---------------------------------------------------------------------------
// Kernel 1: embedding gather -> x (swizzled layout) as f16 hi/lo pairs.
// Thread <-> x granule: gid = g*8192 + b. Coalesced writes.
// Also zeroes the f64 accumulators.
// ---------------------------------------------------------------------------
__global__ __launch_bounds__(256) void gather_kernel(
    const int* __restrict__ x_p, const int* __restrict__ x_a,
    const int* __restrict__ x_c,
    const float* __restrict__ E0, const float* __restrict__ E1,
    const float* __restrict__ E2,
    _Float16* __restrict__ xdh, _Float16* __restrict__ xdl,
    _Float16* __restrict__ xsh, _Float16* __restrict__ xsl,
    double* __restrict__ stats, double* __restrict__ bce_acc) {
  if (blockIdx.x == 0 && threadIdx.x < 18) {
    if (threadIdx.x < 16) stats[threadIdx.x] = 0.0;
    else bce_acc[threadIdx.x - 16] = 0.0;
  }
  int gid = blockIdx.x * 256 + threadIdx.x;   // [0, 786432)
  int g = gid >> 13;                          // granule column 0..95
  int b = gid & 8191;
  int f0 = g * 8;
  int half_ = f0 >= 384;
  int w = f0 - 384 * half_;                   // 0..376, mult of 8
  int tbl = w >> 7;
  int c0 = (w & 127) + (half_ << 7);          // col in E row (8-aligned)
  int row;
  const float* E;
  if (tbl == 0)      { E = E0; row = x_p[b]; }
  else if (tbl == 1) { E = E1; row = x_a[b]; }
  else               { E = E2; row = x_c[b]; }
  const float* src = &E[(size_t)row * 256 + c0];
  f32x4 v0 = *(const f32x4*)src;
  f32x4 v1 = *(const f32x4*)(src + 4);
  half8 h, l;
#pragma unroll
  for (int i = 0; i < 4; ++i) {
    h[i] = (_Float16)v0[i];
    l[i] = (_Float16)(v0[i] - (float)h[i]);
    h[i + 4] = (_Float16)v1[i];
    l[i + 4] = (_Float16)(v1[i] - (float)h[i + 4]);
  }
  size_t o = (size_t)gid * 8;
  *(half8*)&xdh[o] = h; *(half8*)&xdl[o] = l;
  *(half8*)&xsh[o] = h; *(half8*)&xsl[o] = l;
}

// ---------------------------------------------------------------------------
// Kernel 1b: split W into f16 hi/lo in swizzled layout
// ---------------------------------------------------------------------------
__global__ __launch_bounds__(256) void split_w_kernel(
    const float* __restrict__ Wd, const float* __restrict__ Ws,
    _Float16* __restrict__ Wh, _Float16* __restrict__ Wl) {
  int gid = blockIdx.x * 256 + threadIdx.x;   // [0, 589824)
  int nl = gid / 73728;                       // 0..7
  int r3 = gid - nl * 73728;
  int t  = r3 / 3072;
  int r4 = r3 - t * 3072;
  int kk = r4 / 768;
  int row = r4 - kk * 768;
  int k0 = t * 32 + kk * 8;
  const float* src = ((nl < 4) ? Wd : Ws) +
                     ((size_t)(nl & 3) * 768 + row) * 768 + k0;
  f32x4 v0 = *(const f32x4*)src;
  f32x4 v1 = *(const f32x4*)(src + 4);
  half8 h, l;
#pragma unroll
  for (int i = 0; i < 4; ++i) {
    h[i] = (_Float16)v0[i];
    l[i] = (_Float16)(v0[i] - (float)h[i]);
    h[i + 4] = (_Float16)v1[i];
    l[i + 4] = (_Float16)(v1[i] - (float)h[i + 4]);
  }
  size_t o = (size_t)gid * 8;
  *(half8*)&Wh[o] = h;
  *(half8*)&Wl[o] = l;
}

// ---------------------------------------------------------------------------
// Kernel 2: MFMA GEMM, f16 hi/lo 3-term split.
// BM=128, BN=192, BK=32, 512 thr = 8 waves (2m x 4n), wave tile 64x48.
// Grid (64,4,2) = 512 blocks; LDS 2x32KB=64KB -> 2 blocks/CU GUARANTEED
// (128KB < 160KB, unlike R2's exact-160KB marginal fit) = 16 waves/CU.
// LDS stages only Ah|Bh|Bl (2048 granules = [0,512)|[512,1280)|[1280,2048),
// transposed slot = kk*rows + r as before -> staging identity-mapped from
// pre-swizzled global (coalesced 1KB per global_load_lds), frag ds_read
// conflict-free (R1/R2-proven 0 conflicts).
// Al comes DIRECT from L2 into registers (4 coalesced b128 loads/wave/step,
// one base + immediate offsets) -> smaller LDS, smaller barrier drain (4
// loads vs 10). MFMA order: Ah*Bh, Ah*Bl, then Al*Bh last so the in-flight
// Al loads are covered by the MFMA cluster.
// ---------------------------------------------------------------------------
__global__ __launch_bounds__(512, 4) void gemm_mfma_kernel(
    const _Float16* __restrict__ xdh, const _Float16* __restrict__ xdl,
    const _Float16* __restrict__ xsh, const _Float16* __restrict__ xsl,
    const _Float16* __restrict__ Wh, const _Float16* __restrict__ Wl,
    const float* __restrict__ bd, const float* __restrict__ bs,
    float* __restrict__ crd, float* __restrict__ crs,
    double* __restrict__ stats, int layer) {
  const int net = blockIdx.z;
  const float* bias = (net ? bs : bd) + layer * DIM;
  float* C = net ? crs : crd;

  const int tid  = threadIdx.x;
  const int wave = tid >> 6, lane = tid & 63;
  const int quad = lane >> 4, l16 = lane & 15;
  const int m0 = blockIdx.x * 128;
  const int n0 = blockIdx.y * 192;

  __shared__ _Float16 lds[2 * 16384];   // 2 x 32 KB

  const _Float16* xh = net ? xsh : xdh;
  const _Float16* xl = net ? xsl : xdl;
  const size_t wpanel = ((size_t)net * NLAYERS + layer) * (size_t)(24 * 4 * 768 * 8);
  const _Float16* wh = Wh + wpanel;
  const _Float16* wl = Wl + wpanel;

  // staging: wave w stages 4 x 64 granules: slots w*256 + j*64 + lane
  const _Float16* gp[4];
  int gstr[4];
  int dbyte[4];
#pragma unroll
  for (int j = 0; j < 4; ++j) {
    int sb = wave * 256 + j * 64;
    dbyte[j] = sb * 16;
    int s = sb + lane;
    if (s < 512) {                     // Ah granules, slot = kk*128 + r
      int kk = s >> 7, r = s & 127;
      gp[j] = xh + (size_t)(kk * 8192 + m0 + r) * 8;
      gstr[j] = 4 * 8192 * 8;          // 262144 halves per K-step
    } else {                           // Bh [512,1280) / Bl [1280,2048)
      int s2 = s - 512;
      int s3 = (s2 >= 768) ? s2 - 768 : s2;
      int kk = (s3 * 683) >> 17;       // s3/192, exact for s3<768
      int r  = s3 - kk * 192;
      gp[j] = ((s2 >= 768) ? wl : wh) + (size_t)(kk * 768 + n0 + r) * 8;
      gstr[j] = 4 * 768 * 8;           // 24576
    }
  }

  const int wm = (wave >> 2) * 64;     // 2 m-waves
  const int wn = (wave & 3) * 48;      // 4 n-waves

  // Al direct-from-L2 base (per-lane); mt offsets are +mt*128 halves (imm)
  const _Float16* alb = xl + (size_t)(quad * 8192 + m0 + wm + l16) * 8;

  f32x4 acc[4][3];
#pragma unroll
  for (int i = 0; i < 4; ++i)
#pragma unroll
    for (int j = 0; j < 3; ++j) acc[i][j] = (f32x4){0.f, 0.f, 0.f, 0.f};

  // prologue: stage t=0 into buffer 0
#pragma unroll
  for (int j = 0; j < 4; ++j)
    async_copy16(gp[j], (char*)lds + dbyte[j]);
  __syncthreads();

  int cur = 0;
  for (int t = 0; t < 24; ++t) {
    if (t < 23) {                      // issue next-tile stage FIRST
#pragma unroll
      for (int j = 0; j < 4; ++j)
        async_copy16(gp[j] + (t + 1) * gstr[j],
                     (char*)lds + (cur ^ 1) * 32768 + dbyte[j]);
    }
    // Al direct loads (register), issued early, consumed last
    const _Float16* alt = alb + t * 262144;
    half8 al[4];
#pragma unroll
    for (int mt = 0; mt < 4; ++mt)
      al[mt] = *(const half8*)(alt + mt * 128);

    const _Float16* L = lds + cur * 16384;
    half8 ah[4], bh[3], bl[3];
#pragma unroll
    for (int mt = 0; mt < 4; ++mt)
      ah[mt] = *(const half8*)&L[(quad * 128 + wm + mt * 16 + l16) * 8];
#pragma unroll
    for (int nt = 0; nt < 3; ++nt) {
      int ss = 512 + quad * 192 + wn + nt * 16 + l16;
      bh[nt] = *(const half8*)&L[ss * 8];
      bl[nt] = *(const half8*)&L[ss * 8 + 6144];   // +768 granules
    }
    __builtin_amdgcn_s_setprio(1);
#pragma unroll
    for (int nt = 0; nt < 3; ++nt)
#pragma unroll
      for (int mt = 0; mt < 4; ++mt)
        acc[mt][nt] = __builtin_amdgcn_mfma_f32_16x16x32_f16(ah[mt], bh[nt], acc[mt][nt], 0, 0, 0);
#pragma unroll
    for (int nt = 0; nt < 3; ++nt)
#pragma unroll
      for (int mt = 0; mt < 4; ++mt)
        acc[mt][nt] = __builtin_amdgcn_mfma_f32_16x16x32_f16(ah[mt], bl[nt], acc[mt][nt], 0, 0, 0);
#pragma unroll
    for (int nt = 0; nt < 3; ++nt)
#pragma unroll
      for (int mt = 0; mt < 4; ++mt)
        acc[mt][nt] = __builtin_amdgcn_mfma_f32_16x16x32_f16(al[mt], bh[nt], acc[mt][nt], 0, 0, 0);
    __builtin_amdgcn_s_setprio(0);
    __syncthreads();                   // next buffer staged & prev reads done
    cur ^= 1;
  }

  // epilogue: bias add, swizzled C store, f64 sum/sumsq -> atomics
  float biasv[3];
#pragma unroll
  for (int nt = 0; nt < 3; ++nt) biasv[nt] = bias[n0 + wn + nt * 16 + l16];

  double S = 0.0, Q = 0.0;
#pragma unroll
  for (int mt = 0; mt < 4; ++mt) {
#pragma unroll
    for (int nt = 0; nt < 3; ++nt) {
      int n = n0 + wn + nt * 16 + l16;       // n&15 == l16
      size_t gbase = (size_t)(n >> 4) * 131072;   // granule col * 8192 * 16
#pragma unroll
      for (int r = 0; r < 4; ++r) {
        int m = m0 + wm + mt * 16 + quad * 4 + r;
        float v = acc[mt][nt][r] + biasv[nt];
        C[gbase + m * 16 + l16] = v;
        S += (double)v;
        Q += (double)v * (double)v;
      }
    }
  }
#pragma unroll
  for (int off = 32; off > 0; off >>= 1) {
    S += __shfl_down(S, off);
    Q += __shfl_down(Q, off);
  }
  double* red = (double*)lds;           // reuse LDS (post-final-barrier)
  if (lane == 0) { red[wave * 2] = S; red[wave * 2 + 1] = Q; }
  __syncthreads();
  if (tid == 0) {
    double s2 = 0.0, q2 = 0.0;
#pragma unroll
    for (int wv = 0; wv < 8; ++wv) { s2 += red[wv * 2]; q2 += red[wv * 2 + 1]; }
    double* st = stats + ((size_t)layer * 2 + net) * 2;
    atomicAdd(&st[0], s2);
    atomicAdd(&st[1], q2);
  }
}

// ---------------------------------------------------------------------------
// Kernel 4: layernorm -> sigmoid -> threefry bernoulli -> x += cross*mask.
// Thread <-> one 16-float C granule (64B). All accesses coalesced.
// ---------------------------------------------------------------------------
__global__ __launch_bounds__(256) void mask_update_kernel(
    _Float16* __restrict__ xdh, _Float16* __restrict__ xdl,
    _Float16* __restrict__ xsh, _Float16* __restrict__ xsl,
    const float* __restrict__ crd, const float* __restrict__ crs,
    const double* __restrict__ stats, int layer,
    uint32_t kd0, uint32_t kd1, uint32_t ks0, uint32_t ks1) {
  const int net = blockIdx.y;
  _Float16* xh = net ? xsh : xdh;
  _Float16* xl = net ? xsl : xdl;
  const float* cr = net ? crs : crd;
  const uint32_t k0 = net ? ks0 : kd0;
  const uint32_t k1 = net ? ks1 : kd1;

  const double invN = 1.0 / (double)NTOT;
  const double* st = stats + ((size_t)layer * 2 + net) * 2;
  double meand = st[0] * invN;
  double vard  = st[1] * invN - meand * meand;
  float m  = (float)meand;
  float sv = (float)vard + 1e-5f;
  float rs = (float)(1.0 / sqrt((double)sv));

  int cg = blockIdx.x * 256 + threadIdx.x;    // [0, 393216)
  int g16 = cg >> 13;                         // 0..47
  int b   = cg & 8191;
  int f0  = g16 * 16;

  f32x4 c4[4];
#pragma unroll
  for (int i = 0; i < 4; ++i) c4[i] = *(const f32x4*)&cr[(size_t)cg * 16 + i * 4];

  size_t xg0 = ((size_t)g16 * 2) * 8192 + b;
  half8 h0 = *(const half8*)&xh[xg0 * 8];
  half8 l0 = *(const half8*)&xl[xg0 * 8];
  half8 h1 = *(const half8*)&xh[(xg0 + 8192) * 8];
  half8 l1 = *(const half8*)&xl[(xg0 + 8192) * 8];
  half8 ho0, lo0, ho1, lo1;

#pragma unroll
  for (int i = 0; i < 16; ++i) {
    float c  = c4[i >> 2][i & 3];
    float ln = (c - m) * rs;
    uint32_t o0, o1;
    threefry2x32(k0, k1, 0u, (uint32_t)(b * 768 + f0 + i), o0, o1);
    uint32_t bits = o0 ^ o1;
    float u = __uint_as_float(0x3F800000u | (bits >> 9)) - 1.0f;
    double e  = dexp(-(double)ln);
    double ue = (double)u;
    float xv = (i < 8) ? ((float)h0[i & 7] + (float)l0[i & 7])
                       : ((float)h1[i & 7] + (float)l1[i & 7]);
    if (ue + ue * e < 1.0) xv += c;           // u < sigmoid(ln)
    _Float16 hh = (_Float16)xv;
    _Float16 ll = (_Float16)(xv - (float)hh);
    if (i < 8) { ho0[i & 7] = hh; lo0[i & 7] = ll; }
    else       { ho1[i & 7] = hh; lo1[i & 7] = ll; }
  }
  *(half8*)&xh[xg0 * 8] = ho0;
  *(half8*)&xl[xg0 * 8] = lo0;
  *(half8*)&xh[(xg0 + 8192) * 8] = ho1;
  *(half8*)&xl[(xg0 + 8192) * 8] = lo1;
}

// ---------------------------------------------------------------------------
// Kernel 5: heads. 128 blocks x 256 thr; block covers 64 rows.
// Thread (q=t>>6, r=t&63): row b0+r, feature-quarter q (24 granules),
// coalesced 1KB loads (wave lanes = consecutive rows, same granule).
// LDS partial reduce, wave 0 finalizes sigmoid/BCE per row, atomics.
// ---------------------------------------------------------------------------
__global__ __launch_bounds__(256) void head_kernel(
    const _Float16* __restrict__ xdh, const _Float16* __restrict__ xdl,
    const _Float16* __restrict__ xsh, const _Float16* __restrict__ xsl,
    const float* __restrict__ wfd, const float* __restrict__ wfs,
    const float* __restrict__ bfd_p, const float* __restrict__ bfs_p,
    const float* __restrict__ y_true,
    float* __restrict__ out, double* __restrict__ bce_acc) {
  const int tq = threadIdx.x >> 6;     // feature quarter 0..3
  const int tb = threadIdx.x & 63;     // row within block
  const int row = blockIdx.x * 64 + tb;

  float dd = 0.f, dsw = 0.f, sd = 0.f, ssw = 0.f;
  const int g0 = tq * 24;
  for (int g = g0; g < g0 + 24; ++g) {
    size_t o = ((size_t)g * 8192 + row) * 8;
    half8 hd = *(const half8*)&xdh[o];
    half8 ld = *(const half8*)&xdl[o];
    half8 hs = *(const half8*)&xsh[o];
    half8 ls = *(const half8*)&xsl[o];
#pragma unroll
    for (int i = 0; i < 8; ++i) {
      float vd = (float)hd[i] + (float)ld[i];
      float vs = (float)hs[i] + (float)ls[i];
      float wd = wfd[g * 8 + i], ws = wfs[g * 8 + i];
      dd  = fmaf(vd, wd, dd);
      dsw = fmaf(vd, ws, dsw);
      sd  = fmaf(vs, wd, sd);
      ssw = fmaf(vs, ws, ssw);
    }
  }
  __shared__ float part[4][64][4];
  part[tq][tb][0] = dd;  part[tq][tb][1] = dsw;
  part[tq][tb][2] = sd;  part[tq][tb][3] = ssw;
  __syncthreads();

  if (threadIdx.x < 64) {
    float DD  = part[0][tb][0] + part[1][tb][0] + part[2][tb][0] + part[3][tb][0];
    float DSW = part[0][tb][1] + part[1][tb][1] + part[2][tb][1] + part[3][tb][1];
    float SD  = part[0][tb][2] + part[1][tb][2] + part[2][tb][2] + part[3][tb][2];
    float SSW = part[0][tb][3] + part[1][tb][3] + part[2][tb][3] + part[3][tb][3];
    float bfd = *bfd_p, bfs = *bfs_p;
    double sdd = sigmoid_d((double)(DD + bfd));    // fc_d(x_d)
    double ssd = sigmoid_d((double)(DSW + bfs));   // fc_s(x_d)
    double sds = sigmoid_d((double)(SD + bfd));    // fc_d(x_s)
    double sss = sigmoid_d((double)(SSW + bfs));   // fc_s(x_s)
    double ypd = 0.5 * (sdd + sss);
    double yps = 0.5 * (sds + ssd);
    out[row] = (float)ypd;
    double y = (double)y_true[row];
    double bce_d = -(y * log(ypd) + (1.0 - y) * log(1.0 - ypd));
    double bce_s = -(y * log(yps) + (1.0 - y) * log(1.0 - yps));
#pragma unroll
    for (int off = 32; off > 0; off >>= 1) {
      bce_d += __shfl_down(bce_d, off);
      bce_s += __shfl_down(bce_s, off);
    }
    if (tb == 0) {
      atomicAdd(&bce_acc[0], bce_d);
      atomicAdd(&bce_acc[1], bce_s);
    }
  }
}

// ---------------------------------------------------------------------------
// Kernel 6: tri_loss from the two BCE accumulators
// ---------------------------------------------------------------------------
__global__ void loss_kernel(const double* __restrict__ bce_acc,
                            float* __restrict__ out_tri) {
  if (threadIdx.x == 0) {
    double loss_d = bce_acc[0] / (double)BATCH;
    double loss_s = bce_acc[1] / (double)BATCH;
    double bce = loss_d + loss_s;
    double wd = fmax(0.0, loss_d - bce);
    double ws = fmax(0.0, loss_s - bce);
    out_tri[0] = (float)(bce + wd * loss_d + ws * loss_s);
  }
}

// ---------------------------------------------------------------------------
// Launch
// ---------------------------------------------------------------------------
extern "C" void kernel_launch(void* const* d_in, const int* in_sizes, int n_in,
                              void* d_out, int out_size, void* d_ws, size_t ws_size,
                              hipStream_t stream) {
  const int* x_p = (const int*)d_in[0];
  const int* x_a = (const int*)d_in[1];
  const int* x_c = (const int*)d_in[2];
  const float* y_true = (const float*)d_in[3];
  const float* E0 = (const float*)d_in[4];
  const float* E1 = (const float*)d_in[5];
  const float* E2 = (const float*)d_in[6];
  const float* Wd = (const float*)d_in[7];
  const float* bd = (const float*)d_in[8];
  const float* Ws = (const float*)d_in[9];
  const float* bs = (const float*)d_in[10];
  const float* wfd = (const float*)d_in[11];
  const float* bfd = (const float*)d_in[12];
  const float* wfs = (const float*)d_in[13];
  const float* bfs = (const float*)d_in[14];
  float* out = (float*)d_out;

  // workspace layout (bytes; doubles 8B-aligned)
  char* p = (char*)d_ws;
  float* crd = (float*)p;                 p += (size_t)NTOT * 4;
  float* crs = (float*)p;                 p += (size_t)NTOT * 4;
  double* stats   = (double*)p;           p += (size_t)16 * 8;   // [layer][net][S,Q]
  double* bce_acc = (double*)p;           p += (size_t)2 * 8;
  _Float16* xdh = (_Float16*)p;           p += (size_t)NTOT * 2;
  _Float16* xdl = (_Float16*)p;           p += (size_t)NTOT * 2;
  _Float16* xsh = (_Float16*)p;           p += (size_t)NTOT * 2;
  _Float16* xsl = (_Float16*)p;           p += (size_t)NTOT * 2;
  _Float16* Wh  = (_Float16*)p;           p += (size_t)2 * NLAYERS * DIM * DIM * 2;
  _Float16* Wl  = (_Float16*)p;           p += (size_t)2 * NLAYERS * DIM * DIM * 2;

  gather_kernel<<<NTOT / 8 / 256, 256, 0, stream>>>(
      x_p, x_a, x_c, E0, E1, E2, xdh, xdl, xsh, xsl, stats, bce_acc);
  split_w_kernel<<<2 * NLAYERS * DIM * DIM / 8 / 256, 256, 0, stream>>>(
      Wd, Ws, Wh, Wl);

  for (int l = 0; l < NLAYERS; ++l) {
    gemm_mfma_kernel<<<dim3(64, 4, 2), 512, 0, stream>>>(
        xdh, xdl, xsh, xsl, Wh, Wl, bd, bs, crd, crs, stats, l);
    uint32_t kd0, kd1, ks0, ks1;
    threefry2x32(0u, 42u, 0u, (uint32_t)l, kd0, kd1);
    threefry2x32(0u, 42u, 0u, (uint32_t)(4 + l), ks0, ks1);
    mask_update_kernel<<<dim3(NTOT / 16 / 256, 2), 256, 0, stream>>>(
        xdh, xdl, xsh, xsl, crd, crs, stats, l, kd0, kd1, ks0, ks1);
  }

  head_kernel<<<BATCH / 64, 256, 0, stream>>>(
      xdh, xdl, xsh, xsl, wfd, wfs, bfd, bfs, y_true, out, bce_acc);
  loss_kernel<<<1, 64, 0, stream>>>(bce_acc, out + BATCH);
}

// Round 4
// 643.514 us; speedup vs baseline: 1.0379x; 1.0379x over previous
//
#include <hip/hip_runtime.h>
#include <hip/hip_bf16.h>
#include <cstdint>
#include <cstddef>

// Problem constants
#define BATCH   8192
#define DIM     768
#define NTOT    6291456      // BATCH*DIM
#define NLAYERS 4

typedef _Float16 half8 __attribute__((ext_vector_type(8)));
typedef float    f32x4 __attribute__((ext_vector_type(4)));

#define AS_GLOBAL __attribute__((address_space(1)))
#define AS_LDS    __attribute__((address_space(3)))

// async 16B global->LDS copy; lds dst is wave-uniform base + lane*16
__device__ __forceinline__ void async_copy16(const void* g, void* l) {
  __builtin_amdgcn_global_load_lds((AS_GLOBAL const uint32_t*)g,
                                   (AS_LDS uint32_t*)l, 16, 0, 0);
}

// ---------------------------------------------------------------------------
// Swizzled global layouts (granule = 8 halves = 16B):
//   x*:  [t 24][kk 4][b 8192][8]          granule idx = (t*4+kk)*8192 + b
//   W*:  [net][layer][t 24][kk 4][row 768][8]
//   cr*: [g16 48][b 8192][16 floats]      g16 = f>>4  (64B granule)
// logical element (b, f): t = f>>5, kk = (f>>3)&3, e = f&7
// ---------------------------------------------------------------------------

// ---------------------------------------------------------------------------
// Threefry-2x32 (matches jax/_src/prng.py exactly; 20 rounds, 5 key injections)
// ---------------------------------------------------------------------------
__host__ __device__ __forceinline__ uint32_t rotl32(uint32_t v, int d) {
  return (v << d) | (v >> (32 - d));
}

__host__ __device__ __forceinline__ void threefry2x32(
    uint32_t k0, uint32_t k1, uint32_t x0, uint32_t x1,
    uint32_t& o0, uint32_t& o1) {
  uint32_t ks2 = k0 ^ k1 ^ 0x1BD11BDAu;
  x0 += k0; x1 += k1;
#define TF_R(r) { x0 += x1; x1 = rotl32(x1, (r)) ^ x0; }
  TF_R(13) TF_R(15) TF_R(26) TF_R(6)
  x0 += k1; x1 += ks2 + 1u;
  TF_R(17) TF_R(29) TF_R(16) TF_R(24)
  x0 += ks2; x1 += k0 + 2u;
  TF_R(13) TF_R(15) TF_R(26) TF_R(6)
  x0 += k0; x1 += k1 + 3u;
  TF_R(17) TF_R(29) TF_R(16) TF_R(24)
  x0 += k1; x1 += ks2 + 4u;
  TF_R(13) TF_R(15) TF_R(26) TF_R(6)
  x0 += ks2; x1 += k0 + 5u;
#undef TF_R
  o0 = x0; o1 = x1;
}

__device__ __forceinline__ double sigmoid_d(double x) {
  return 1.0 / (1.0 + exp(-x));
}

// fast f64 e^x, clamped, rel err ~2e-13
__device__ __forceinline__ double dexp(double x) {
  x = fmin(fmax(x, -708.0), 708.0);
  const double LOG2E = 1.4426950408889634;
  const double LN2   = 0.6931471805599453;
  double t = x * LOG2E;
  double n = rint(t);
  double g = (t - n) * LN2;
  double r = 2.7557319223985893e-07;
  r = r * g + 2.7557319223985888e-06;
  r = r * g + 2.4801587301587302e-05;
  r = r * g + 1.9841269841269841e-04;
  r = r * g + 1.3888888888888889e-03;
  r = r * g + 8.3333333333333332e-03;
  r = r * g + 4.1666666666666664e-02;
  r = r * g + 1.6666666666666666e-01;
  r = r * g + 0.5;
  r = r * g + 1.0;
  r = r * g + 1.0;
  int ni = (int)n;
  double sc = __longlong_as_double(((long long)(1023 + ni)) << 52);
  return r * sc;
}

// ---------------------------------------------------------------------------
// Kernel 1: embedding gather -> x (swizzled layout) as f16 hi/lo pairs.
// ---------------------------------------------------------------------------
__global__ __launch_bounds__(256) void gather_kernel(
    const int* __restrict__ x_p, const int* __restrict__ x_a,
    const int* __restrict__ x_c,
    const float* __restrict__ E0, const float* __restrict__ E1,
    const float* __restrict__ E2,
    _Float16* __restrict__ xdh, _Float16* __restrict__ xdl,
    _Float16* __restrict__ xsh, _Float16* __restrict__ xsl,
    double* __restrict__ stats, double* __restrict__ bce_acc) {
  if (blockIdx.x == 0 && threadIdx.x < 18) {
    if (threadIdx.x < 16) stats[threadIdx.x] = 0.0;
    else bce_acc[threadIdx.x - 16] = 0.0;
  }
  int gid = blockIdx.x * 256 + threadIdx.x;   // [0, 786432)
  int g = gid >> 13;                          // granule column 0..95
  int b = gid & 8191;
  int f0 = g * 8;
  int half_ = f0 >= 384;
  int w = f0 - 384 * half_;                   // 0..376, mult of 8
  int tbl = w >> 7;
  int c0 = (w & 127) + (half_ << 7);          // col in E row (8-aligned)
  int row;
  const float* E;
  if (tbl == 0)      { E = E0; row = x_p[b]; }
  else if (tbl == 1) { E = E1; row = x_a[b]; }
  else               { E = E2; row = x_c[b]; }
  const float* src = &E[(size_t)row * 256 + c0];
  f32x4 v0 = *(const f32x4*)src;
  f32x4 v1 = *(const f32x4*)(src + 4);
  half8 h, l;
#pragma unroll
  for (int i = 0; i < 4; ++i) {
    h[i] = (_Float16)v0[i];
    l[i] = (_Float16)(v0[i] - (float)h[i]);
    h[i + 4] = (_Float16)v1[i];
    l[i + 4] = (_Float16)(v1[i] - (float)h[i + 4]);
  }
  size_t o = (size_t)gid * 8;
  *(half8*)&xdh[o] = h; *(half8*)&xdl[o] = l;
  *(half8*)&xsh[o] = h; *(half8*)&xsl[o] = l;
}

// ---------------------------------------------------------------------------
// Kernel 1b: split W into f16 hi/lo in swizzled layout
// ---------------------------------------------------------------------------
__global__ __launch_bounds__(256) void split_w_kernel(
    const float* __restrict__ Wd, const float* __restrict__ Ws,
    _Float16* __restrict__ Wh, _Float16* __restrict__ Wl) {
  int gid = blockIdx.x * 256 + threadIdx.x;   // [0, 589824)
  int nl = gid / 73728;                       // 0..7
  int r3 = gid - nl * 73728;
  int t  = r3 / 3072;
  int r4 = r3 - t * 3072;
  int kk = r4 / 768;
  int row = r4 - kk * 768;
  int k0 = t * 32 + kk * 8;
  const float* src = ((nl < 4) ? Wd : Ws) +
                     ((size_t)(nl & 3) * 768 + row) * 768 + k0;
  f32x4 v0 = *(const f32x4*)src;
  f32x4 v1 = *(const f32x4*)(src + 4);
  half8 h, l;
#pragma unroll
  for (int i = 0; i < 4; ++i) {
    h[i] = (_Float16)v0[i];
    l[i] = (_Float16)(v0[i] - (float)h[i]);
    h[i + 4] = (_Float16)v1[i];
    l[i + 4] = (_Float16)(v1[i] - (float)h[i + 4]);
  }
  size_t o = (size_t)gid * 8;
  *(half8*)&Wh[o] = h;
  *(half8*)&Wl[o] = l;
}

// ---------------------------------------------------------------------------
// Kernel 2: MFMA GEMM, f16 hi/lo 3-term split, PHASE-INTERLEAVED (T3+T4).
// BM=256, BN=192, BK=32, 512 thr = 8 waves (4m x 2n), wave tile 64x96.
// Grid (32,4,2) = 256 blocks = exactly 1 block/CU. LDS 2x56KB = 112 KB.
// Buffer slot map (granules, 3584 total):
//   Ah [0,1024): kk*256+r | Al [1024,2048) | Bh [2048,2816): kk*192+r |
//   Bl [2816,3584)
// Staging identity-mapped from pre-swizzled global (1KB coalesced per
// global_load_lds, 7 loads/wave/step); frag ds_read conflict-free (proven
// 0 conflicts R2/R3).
// Schedule per K-step (the T4 counted-vmcnt pattern; never drains in-loop):
//   s_barrier                     // all waves done reading buf^1 (step t-1)
//   issue 7 loads (tile t+1 -> buf^1)
//   s_waitcnt vmcnt(7)            // tile t landed; t+1 stays IN FLIGHT
//   s_barrier                     // buf^0 visible to all
//   3 phases: {ds_read subtile; s_barrier; setprio(1); 24 MFMA; setprio(0);
//              s_barrier}        // phase role-split -> T5 active
// Compiler tracks ds_read->MFMA lgkmcnt automatically (plain C++ reads);
// sched_barrier(0) after asm waits per rule #18.
// ---------------------------------------------------------------------------
__global__ __launch_bounds__(512, 2) void gemm_mfma_kernel(
    const _Float16* __restrict__ xdh, const _Float16* __restrict__ xdl,
    const _Float16* __restrict__ xsh, const _Float16* __restrict__ xsl,
    const _Float16* __restrict__ Wh, const _Float16* __restrict__ Wl,
    const float* __restrict__ bd, const float* __restrict__ bs,
    float* __restrict__ crd, float* __restrict__ crs,
    double* __restrict__ stats, int layer) {
  const int net = blockIdx.z;
  const float* bias = (net ? bs : bd) + layer * DIM;
  float* C = net ? crs : crd;

  const int tid  = threadIdx.x;
  const int wave = tid >> 6, lane = tid & 63;
  const int quad = lane >> 4, l16 = lane & 15;
  const int m0 = blockIdx.x * 256;
  const int n0 = blockIdx.y * 192;

  __shared__ _Float16 lds[2 * 28672];   // 2 x 56 KB

  const _Float16* xh = net ? xsh : xdh;
  const _Float16* xl = net ? xsl : xdl;
  const size_t wpanel = ((size_t)net * NLAYERS + layer) * (size_t)(24 * 4 * 768 * 8);
  const _Float16* wh = Wh + wpanel;
  const _Float16* wl = Wl + wpanel;

  // staging: wave w covers granule slots [w*448, (w+1)*448), 7 instrs
  const _Float16* gp[7];
  int gstr[7];
  int dbyte[7];
#pragma unroll
  for (int j = 0; j < 7; ++j) {
    int sb = wave * 448 + j * 64;
    dbyte[j] = sb * 16;
    int s = sb + lane;
    if (s < 2048) {                    // Ah [0,1024) / Al [1024,2048)
      int s2 = s & 1023;
      int kk = s2 >> 8, r = s2 & 255;
      gp[j] = ((s < 1024) ? xh : xl) + (size_t)(kk * 8192 + m0 + r) * 8;
      gstr[j] = 4 * 8192 * 8;          // 262144 halves per K-step
    } else {                           // Bh [2048,2816) / Bl [2816,3584)
      int s2 = s - 2048;
      int s3 = (s2 >= 768) ? s2 - 768 : s2;
      int kk = (s3 * 683) >> 17;       // s3/192, exact for s3<768
      int r  = s3 - kk * 192;
      gp[j] = ((s2 >= 768) ? wl : wh) + (size_t)(kk * 768 + n0 + r) * 8;
      gstr[j] = 4 * 768 * 8;           // 24576
    }
  }

  const int wm = (wave >> 1) * 64;     // 4 m-waves
  const int wn = (wave & 1) * 96;      // 2 n-waves

  f32x4 acc[4][6];
#pragma unroll
  for (int i = 0; i < 4; ++i)
#pragma unroll
    for (int j = 0; j < 6; ++j) acc[i][j] = (f32x4){0.f, 0.f, 0.f, 0.f};

  // prologue: stage tile 0 into buffer 0
#pragma unroll
  for (int j = 0; j < 7; ++j)
    async_copy16(gp[j], (char*)lds + dbyte[j]);

  int cur = 0;
  for (int t = 0; t < 24; ++t) {
    __builtin_amdgcn_s_barrier();      // all waves done reading buf^1
    if (t < 23) {
#pragma unroll
      for (int j = 0; j < 7; ++j)
        async_copy16(gp[j] + (t + 1) * gstr[j],
                     (char*)lds + (cur ^ 1) * 57344 + dbyte[j]);
      asm volatile("s_waitcnt vmcnt(7)" ::: "memory");  // tile t landed
    } else {
      asm volatile("s_waitcnt vmcnt(0)" ::: "memory");
    }
    __builtin_amdgcn_sched_barrier(0);
    __builtin_amdgcn_s_barrier();      // buf[cur] visible to all waves

    const _Float16* L = lds + cur * 28672;
    half8 ah[4], al[4], bh[2], bl[2];

    // ---- phase 0: A frags + B cols 0,1 ----
#pragma unroll
    for (int mt = 0; mt < 4; ++mt) {
      int sl = quad * 256 + wm + mt * 16 + l16;
      ah[mt] = *(const half8*)&L[sl * 8];
      al[mt] = *(const half8*)&L[sl * 8 + 8192];
    }
#pragma unroll
    for (int nt = 0; nt < 2; ++nt) {
      int ss = 2048 + quad * 192 + wn + nt * 16 + l16;
      bh[nt] = *(const half8*)&L[ss * 8];
      bl[nt] = *(const half8*)&L[ss * 8 + 6144];
    }
    __builtin_amdgcn_s_barrier();
    __builtin_amdgcn_s_setprio(1);
#pragma unroll
    for (int nt = 0; nt < 2; ++nt)
#pragma unroll
      for (int mt = 0; mt < 4; ++mt) {
        f32x4 a = acc[mt][nt];
        a = __builtin_amdgcn_mfma_f32_16x16x32_f16(ah[mt], bh[nt], a, 0, 0, 0);
        a = __builtin_amdgcn_mfma_f32_16x16x32_f16(al[mt], bh[nt], a, 0, 0, 0);
        a = __builtin_amdgcn_mfma_f32_16x16x32_f16(ah[mt], bl[nt], a, 0, 0, 0);
        acc[mt][nt] = a;
      }
    __builtin_amdgcn_s_setprio(0);
    __builtin_amdgcn_s_barrier();

    // ---- phase 1: B cols 2,3 ----
#pragma unroll
    for (int nt = 0; nt < 2; ++nt) {
      int ss = 2048 + quad * 192 + wn + (nt + 2) * 16 + l16;
      bh[nt] = *(const half8*)&L[ss * 8];
      bl[nt] = *(const half8*)&L[ss * 8 + 6144];
    }
    __builtin_amdgcn_s_barrier();
    __builtin_amdgcn_s_setprio(1);
#pragma unroll
    for (int nt = 0; nt < 2; ++nt)
#pragma unroll
      for (int mt = 0; mt < 4; ++mt) {
        f32x4 a = acc[mt][nt + 2];
        a = __builtin_amdgcn_mfma_f32_16x16x32_f16(ah[mt], bh[nt], a, 0, 0, 0);
        a = __builtin_amdgcn_mfma_f32_16x16x32_f16(al[mt], bh[nt], a, 0, 0, 0);
        a = __builtin_amdgcn_mfma_f32_16x16x32_f16(ah[mt], bl[nt], a, 0, 0, 0);
        acc[mt][nt + 2] = a;
      }
    __builtin_amdgcn_s_setprio(0);
    __builtin_amdgcn_s_barrier();

    // ---- phase 2: B cols 4,5 ----
#pragma unroll
    for (int nt = 0; nt < 2; ++nt) {
      int ss = 2048 + quad * 192 + wn + (nt + 4) * 16 + l16;
      bh[nt] = *(const half8*)&L[ss * 8];
      bl[nt] = *(const half8*)&L[ss * 8 + 6144];
    }
    __builtin_amdgcn_s_barrier();
    __builtin_amdgcn_s_setprio(1);
#pragma unroll
    for (int nt = 0; nt < 2; ++nt)
#pragma unroll
      for (int mt = 0; mt < 4; ++mt) {
        f32x4 a = acc[mt][nt + 4];
        a = __builtin_amdgcn_mfma_f32_16x16x32_f16(ah[mt], bh[nt], a, 0, 0, 0);
        a = __builtin_amdgcn_mfma_f32_16x16x32_f16(al[mt], bh[nt], a, 0, 0, 0);
        a = __builtin_amdgcn_mfma_f32_16x16x32_f16(ah[mt], bl[nt], a, 0, 0, 0);
        acc[mt][nt + 4] = a;
      }
    __builtin_amdgcn_s_setprio(0);
    cur ^= 1;
  }

  __syncthreads();   // full sync before epilogue LDS reuse

  // epilogue: bias add, swizzled C store, f64 sum/sumsq -> atomics
  float biasv[6];
#pragma unroll
  for (int nt = 0; nt < 6; ++nt) biasv[nt] = bias[n0 + wn + nt * 16 + l16];

  double S = 0.0, Q = 0.0;
#pragma unroll
  for (int mt = 0; mt < 4; ++mt) {
#pragma unroll
    for (int nt = 0; nt < 6; ++nt) {
      int n = n0 + wn + nt * 16 + l16;            // n&15 == l16
      size_t gbase = (size_t)(n >> 4) * 131072;   // granule col * 8192*16
#pragma unroll
      for (int r = 0; r < 4; ++r) {
        int m = m0 + wm + mt * 16 + quad * 4 + r;
        float v = acc[mt][nt][r] + biasv[nt];
        C[gbase + m * 16 + l16] = v;
        S += (double)v;
        Q += (double)v * (double)v;
      }
    }
  }
#pragma unroll
  for (int off = 32; off > 0; off >>= 1) {
    S += __shfl_down(S, off);
    Q += __shfl_down(Q, off);
  }
  double* red = (double*)lds;           // reuse LDS (post-final-barrier)
  if (lane == 0) { red[wave * 2] = S; red[wave * 2 + 1] = Q; }
  __syncthreads();
  if (tid == 0) {
    double s2 = 0.0, q2 = 0.0;
#pragma unroll
    for (int wv = 0; wv < 8; ++wv) { s2 += red[wv * 2]; q2 += red[wv * 2 + 1]; }
    double* st = stats + ((size_t)layer * 2 + net) * 2;
    atomicAdd(&st[0], s2);
    atomicAdd(&st[1], q2);
  }
}

// ---------------------------------------------------------------------------
// Kernel 4: layernorm -> sigmoid -> threefry bernoulli -> x += cross*mask.
// Thread <-> one 16-float C granule (64B). All accesses coalesced.
// ---------------------------------------------------------------------------
__global__ __launch_bounds__(256) void mask_update_kernel(
    _Float16* __restrict__ xdh, _Float16* __restrict__ xdl,
    _Float16* __restrict__ xsh, _Float16* __restrict__ xsl,
    const float* __restrict__ crd, const float* __restrict__ crs,
    const double* __restrict__ stats, int layer,
    uint32_t kd0, uint32_t kd1, uint32_t ks0, uint32_t ks1) {
  const int net = blockIdx.y;
  _Float16* xh = net ? xsh : xdh;
  _Float16* xl = net ? xsl : xdl;
  const float* cr = net ? crs : crd;
  const uint32_t k0 = net ? ks0 : kd0;
  const uint32_t k1 = net ? ks1 : kd1;

  const double invN = 1.0 / (double)NTOT;
  const double* st = stats + ((size_t)layer * 2 + net) * 2;
  double meand = st[0] * invN;
  double vard  = st[1] * invN - meand * meand;
  float m  = (float)meand;
  float sv = (float)vard + 1e-5f;
  float rs = (float)(1.0 / sqrt((double)sv));

  int cg = blockIdx.x * 256 + threadIdx.x;    // [0, 393216)
  int g16 = cg >> 13;                         // 0..47
  int b   = cg & 8191;
  int f0  = g16 * 16;

  f32x4 c4[4];
#pragma unroll
  for (int i = 0; i < 4; ++i) c4[i] = *(const f32x4*)&cr[(size_t)cg * 16 + i * 4];

  size_t xg0 = ((size_t)g16 * 2) * 8192 + b;
  half8 h0 = *(const half8*)&xh[xg0 * 8];
  half8 l0 = *(const half8*)&xl[xg0 * 8];
  half8 h1 = *(const half8*)&xh[(xg0 + 8192) * 8];
  half8 l1 = *(const half8*)&xl[(xg0 + 8192) * 8];
  half8 ho0, lo0, ho1, lo1;

#pragma unroll
  for (int i = 0; i < 16; ++i) {
    float c  = c4[i >> 2][i & 3];
    float ln = (c - m) * rs;
    uint32_t o0, o1;
    threefry2x32(k0, k1, 0u, (uint32_t)(b * 768 + f0 + i), o0, o1);
    uint32_t bits = o0 ^ o1;
    float u = __uint_as_float(0x3F800000u | (bits >> 9)) - 1.0f;
    double e  = dexp(-(double)ln);
    double ue = (double)u;
    float xv = (i < 8) ? ((float)h0[i & 7] + (float)l0[i & 7])
                       : ((float)h1[i & 7] + (float)l1[i & 7]);
    if (ue + ue * e < 1.0) xv += c;           // u < sigmoid(ln)
    _Float16 hh = (_Float16)xv;
    _Float16 ll = (_Float16)(xv - (float)hh);
    if (i < 8) { ho0[i & 7] = hh; lo0[i & 7] = ll; }
    else       { ho1[i & 7] = hh; lo1[i & 7] = ll; }
  }
  *(half8*)&xh[xg0 * 8] = ho0;
  *(half8*)&xl[xg0 * 8] = lo0;
  *(half8*)&xh[(xg0 + 8192) * 8] = ho1;
  *(half8*)&xl[(xg0 + 8192) * 8] = lo1;
}

// ---------------------------------------------------------------------------
// Kernel 5: heads. 128 blocks x 256 thr; block covers 64 rows.
// Thread (q=t>>6, r=t&63): row b0+r, feature-quarter q (24 granules),
// coalesced loads; LDS partial reduce; wave 0 finalizes BCE per row.
// ---------------------------------------------------------------------------
__global__ __launch_bounds__(256) void head_kernel(
    const _Float16* __restrict__ xdh, const _Float16* __restrict__ xdl,
    const _Float16* __restrict__ xsh, const _Float16* __restrict__ xsl,
    const float* __restrict__ wfd, const float* __restrict__ wfs,
    const float* __restrict__ bfd_p, const float* __restrict__ bfs_p,
    const float* __restrict__ y_true,
    float* __restrict__ out, double* __restrict__ bce_acc) {
  const int tq = threadIdx.x >> 6;     // feature quarter 0..3
  const int tb = threadIdx.x & 63;     // row within block
  const int row = blockIdx.x * 64 + tb;

  float dd = 0.f, dsw = 0.f, sd = 0.f, ssw = 0.f;
  const int g0 = tq * 24;
  for (int g = g0; g < g0 + 24; ++g) {
    size_t o = ((size_t)g * 8192 + row) * 8;
    half8 hd = *(const half8*)&xdh[o];
    half8 ld = *(const half8*)&xdl[o];
    half8 hs = *(const half8*)&xsh[o];
    half8 ls = *(const half8*)&xsl[o];
#pragma unroll
    for (int i = 0; i < 8; ++i) {
      float vd = (float)hd[i] + (float)ld[i];
      float vs = (float)hs[i] + (float)ls[i];
      float wd = wfd[g * 8 + i], ws = wfs[g * 8 + i];
      dd  = fmaf(vd, wd, dd);
      dsw = fmaf(vd, ws, dsw);
      sd  = fmaf(vs, wd, sd);
      ssw = fmaf(vs, ws, ssw);
    }
  }
  __shared__ float part[4][64][4];
  part[tq][tb][0] = dd;  part[tq][tb][1] = dsw;
  part[tq][tb][2] = sd;  part[tq][tb][3] = ssw;
  __syncthreads();

  if (threadIdx.x < 64) {
    float DD  = part[0][tb][0] + part[1][tb][0] + part[2][tb][0] + part[3][tb][0];
    float DSW = part[0][tb][1] + part[1][tb][1] + part[2][tb][1] + part[3][tb][1];
    float SD  = part[0][tb][2] + part[1][tb][2] + part[2][tb][2] + part[3][tb][2];
    float SSW = part[0][tb][3] + part[1][tb][3] + part[2][tb][3] + part[3][tb][3];
    float bfd = *bfd_p, bfs = *bfs_p;
    double sdd = sigmoid_d((double)(DD + bfd));    // fc_d(x_d)
    double ssd = sigmoid_d((double)(DSW + bfs));   // fc_s(x_d)
    double sds = sigmoid_d((double)(SD + bfd));    // fc_d(x_s)
    double sss = sigmoid_d((double)(SSW + bfs));   // fc_s(x_s)
    double ypd = 0.5 * (sdd + sss);
    double yps = 0.5 * (sds + ssd);
    out[row] = (float)ypd;
    double y = (double)y_true[row];
    double bce_d = -(y * log(ypd) + (1.0 - y) * log(1.0 - ypd));
    double bce_s = -(y * log(yps) + (1.0 - y) * log(1.0 - yps));
#pragma unroll
    for (int off = 32; off > 0; off >>= 1) {
      bce_d += __shfl_down(bce_d, off);
      bce_s += __shfl_down(bce_s, off);
    }
    if (tb == 0) {
      atomicAdd(&bce_acc[0], bce_d);
      atomicAdd(&bce_acc[1], bce_s);
    }
  }
}

// ---------------------------------------------------------------------------
// Kernel 6: tri_loss from the two BCE accumulators
// ---------------------------------------------------------------------------
__global__ void loss_kernel(const double* __restrict__ bce_acc,
                            float* __restrict__ out_tri) {
  if (threadIdx.x == 0) {
    double loss_d = bce_acc[0] / (double)BATCH;
    double loss_s = bce_acc[1] / (double)BATCH;
    double bce = loss_d + loss_s;
    double wd = fmax(0.0, loss_d - bce);
    double ws = fmax(0.0, loss_s - bce);
    out_tri[0] = (float)(bce + wd * loss_d + ws * loss_s);
  }
}

// ---------------------------------------------------------------------------
// Launch
// ---------------------------------------------------------------------------
extern "C" void kernel_launch(void* const* d_in, const int* in_sizes, int n_in,
                              void* d_out, int out_size, void* d_ws, size_t ws_size,
                              hipStream_t stream) {
  const int* x_p = (const int*)d_in[0];
  const int* x_a = (const int*)d_in[1];
  const int* x_c = (const int*)d_in[2];
  const float* y_true = (const float*)d_in[3];
  const float* E0 = (const float*)d_in[4];
  const float* E1 = (const float*)d_in[5];
  const float* E2 = (const float*)d_in[6];
  const float* Wd = (const float*)d_in[7];
  const float* bd = (const float*)d_in[8];
  const float* Ws = (const float*)d_in[9];
  const float* bs = (const float*)d_in[10];
  const float* wfd = (const float*)d_in[11];
  const float* bfd = (const float*)d_in[12];
  const float* wfs = (const float*)d_in[13];
  const float* bfs = (const float*)d_in[14];
  float* out = (float*)d_out;

  // workspace layout (bytes; doubles 8B-aligned)
  char* p = (char*)d_ws;
  float* crd = (float*)p;                 p += (size_t)NTOT * 4;
  float* crs = (float*)p;                 p += (size_t)NTOT * 4;
  double* stats   = (double*)p;           p += (size_t)16 * 8;   // [layer][net][S,Q]
  double* bce_acc = (double*)p;           p += (size_t)2 * 8;
  _Float16* xdh = (_Float16*)p;           p += (size_t)NTOT * 2;
  _Float16* xdl = (_Float16*)p;           p += (size_t)NTOT * 2;
  _Float16* xsh = (_Float16*)p;           p += (size_t)NTOT * 2;
  _Float16* xsl = (_Float16*)p;           p += (size_t)NTOT * 2;
  _Float16* Wh  = (_Float16*)p;           p += (size_t)2 * NLAYERS * DIM * DIM * 2;
  _Float16* Wl  = (_Float16*)p;           p += (size_t)2 * NLAYERS * DIM * DIM * 2;

  gather_kernel<<<NTOT / 8 / 256, 256, 0, stream>>>(
      x_p, x_a, x_c, E0, E1, E2, xdh, xdl, xsh, xsl, stats, bce_acc);
  split_w_kernel<<<2 * NLAYERS * DIM * DIM / 8 / 256, 256, 0, stream>>>(
      Wd, Ws, Wh, Wl);

  for (int l = 0; l < NLAYERS; ++l) {
    gemm_mfma_kernel<<<dim3(32, 4, 2), 512, 0, stream>>>(
        xdh, xdl, xsh, xsl, Wh, Wl, bd, bs, crd, crs, stats, l);
    uint32_t kd0, kd1, ks0, ks1;
    threefry2x32(0u, 42u, 0u, (uint32_t)l, kd0, kd1);
    threefry2x32(0u, 42u, 0u, (uint32_t)(4 + l), ks0, ks1);
    mask_update_kernel<<<dim3(NTOT / 16 / 256, 2), 256, 0, stream>>>(
        xdh, xdl, xsh, xsl, crd, crs, stats, l, kd0, kd1, ks0, ks1);
  }

  head_kernel<<<BATCH / 64, 256, 0, stream>>>(
      xdh, xdl, xsh, xsl, wfd, wfs, bfd, bfs, y_true, out, bce_acc);
  loss_kernel<<<1, 64, 0, stream>>>(bce_acc, out + BATCH);
}